// Round 7
// baseline (105.193 us; speedup 1.0000x reference)
//
#include <hip/hip_runtime.h>
#include <hip/hip_fp16.h>

#define N_ 16
#define C_ 128
#define S_ 16384
#define K_ 64

typedef __attribute__((ext_vector_type(4))) float f32x4;
typedef __attribute__((ext_vector_type(8))) _Float16 f16x8;
typedef __attribute__((ext_vector_type(4))) _Float16 f16x4;

// xT row-swizzle: varies with staging rows s=4*s4+j AND frag rows s=16m+lr.
#define SWZ_S(s) ((((s) ^ ((s) >> 3)) & 7) << 3)

// ---------------------------------------------------------------------------
// Fused v4: single xC, 3 barriers/tile, 40.5 KB LDS -> 3 blocks/CU; grid 768
// (= exactly 3/CU, all resident, zero tail). Flat tile space: 4096 tiles of
// 64 s; block b owns 5-6 contiguous tiles, vacc flushed by atomicAdd on
// n-boundary/end. W fragments in registers. rns double-buffered (rotation).
// ---------------------------------------------------------------------------
__global__ __launch_bounds__(256, 3) void fused_kernel(
    const float* __restrict__ x, const float* __restrict__ fc_w,
    const float* __restrict__ fc_b, float* __restrict__ vlad_acc,
    float* __restrict__ a_sum)
{
    __shared__ _Float16 xT[64 * 128];    // 16 KB [s][c]
    __shared__ _Float16 xC[128 * 64];    // 16 KB [c][s]
    __shared__ _Float16 sst[64 * 64];    //  8 KB [k][s]
    __shared__ float rns[2][64];         // 512 B, rotation-zeroed

    const int tid = threadIdx.x;
    const int lane = tid & 63, w = tid >> 6;
    const int lr = lane & 15, g = lane >> 4;
    const int fsw = (lr & 7) << 3;       // swizzle for rows of form m*16+lr

    // block's tile range: 256 blocks x 6 tiles + 512 blocks x 5 tiles = 4096
    const int b = blockIdx.x;
    const int lo  = (b < 256) ? b * 6 : 1536 + (b - 256) * 5;
    const int cnt = (b < 256) ? 6 : 5;

    // ---- W B-fragments in registers (tile/n-invariant) ----
    f16x8 wfrag[4][4];
#pragma unroll
    for (int nt = 0; nt < 4; ++nt)
#pragma unroll
        for (int kt = 0; kt < 4; ++kt) {
            const float* wp = fc_w + (nt * 16 + lr) * C_ + kt * 32 + g * 8;
            float4 wa = *(const float4*)wp;
            float4 wb = *(const float4*)(wp + 4);
            f16x8 f;
            f[0] = (_Float16)wa.x; f[1] = (_Float16)wa.y;
            f[2] = (_Float16)wa.z; f[3] = (_Float16)wa.w;
            f[4] = (_Float16)wb.x; f[5] = (_Float16)wb.y;
            f[6] = (_Float16)wb.z; f[7] = (_Float16)wb.w;
            wfrag[nt][kt] = f;
        }
    if (tid < 128) (&rns[0][0])[tid] = 0.f;   // zero both rns buffers

    float bias[4];
#pragma unroll
    for (int nt = 0; nt < 4; ++nt) bias[nt] = fc_b[nt * 16 + lr];
    float a_acc[4] = {0.f, 0.f, 0.f, 0.f};
    f32x4 vacc[8];
#pragma unroll
    for (int nt = 0; nt < 8; ++nt) vacc[nt] = (f32x4){0.f, 0.f, 0.f, 0.f};

    const int s4 = tid & 15;
    int cqv[2];
#pragma unroll
    for (int i = 0; i < 2; ++i) cqv[i] = i * 16 + (tid >> 4);

    auto flush = [&](int nn) {
        float* vp = vlad_acc + ((size_t)nn * K_ + w * 16) * C_;
#pragma unroll
        for (int nt = 0; nt < 8; ++nt) {
#pragma unroll
            for (int r = 0; r < 4; ++r)
                atomicAdd(vp + (g * 4 + r) * C_ + nt * 16 + lr, vacc[nt][r]);
            vacc[nt] = (f32x4){0.f, 0.f, 0.f, 0.f};
        }
#pragma unroll
        for (int nt = 0; nt < 4; ++nt) {
            a_acc[nt] += __shfl_xor(a_acc[nt], 16);
            a_acc[nt] += __shfl_xor(a_acc[nt], 32);
        }
        if (lane < 16) {
#pragma unroll
            for (int nt = 0; nt < 4; ++nt)
                atomicAdd(a_sum + nn * K_ + nt * 16 + lr, a_acc[nt]);
        }
#pragma unroll
        for (int nt = 0; nt < 4; ++nt) a_acc[nt] = 0.f;
    };

    // prefetch first tile
    float4 pre[2][4];
    {
        const int n0 = lo >> 8, ss = (lo & 255) << 6;
        const float* xb = x + (size_t)n0 * C_ * S_ + ss;
#pragma unroll
        for (int i = 0; i < 2; ++i)
#pragma unroll
            for (int cc = 0; cc < 4; ++cc)
                pre[i][cc] = *(const float4*)(xb + (size_t)(cqv[i] * 4 + cc) * S_ + s4 * 4);
    }

    int ncur = lo >> 8;

#pragma unroll 1
    for (int it = 0; it < cnt; ++it) {
        const int tau = lo + it;
        const int n = tau >> 8;
        if (n != ncur) { flush(ncur); ncur = n; }   // reg-private, no sync needed

        __syncthreads();   // A: xT/xC/sst free (vlad(it-1) done); rns init @it=0

        // ---- stage tile: xT (4x4 transpose) + xC + norm partials ----
        float part[4] = {0.f, 0.f, 0.f, 0.f};
#pragma unroll
        for (int i = 0; i < 2; ++i) {
            int cq = cqv[i];
#pragma unroll
            for (int j = 0; j < 4; ++j) {
                float v0 = (&pre[i][0].x)[j], v1 = (&pre[i][1].x)[j],
                      v2 = (&pre[i][2].x)[j], v3 = (&pre[i][3].x)[j];
                part[j] += v0 * v0 + v1 * v1 + v2 * v2 + v3 * v3;
                f16x4 p = {(_Float16)v0, (_Float16)v1, (_Float16)v2, (_Float16)v3};
                int s = s4 * 4 + j;
                *(f16x4*)&xT[s * 128 + ((cq * 4) ^ SWZ_S(s))] = p;
            }
#pragma unroll
            for (int cc = 0; cc < 4; ++cc) {
                int c = cq * 4 + cc;
                f16x4 q = {(_Float16)pre[i][cc].x, (_Float16)pre[i][cc].y,
                           (_Float16)pre[i][cc].z, (_Float16)pre[i][cc].w};
                *(f16x4*)&xC[c * 64 + ((s4 * 4) ^ ((c & 7) << 3))] = q;
            }
        }
#pragma unroll
        for (int j = 0; j < 4; ++j) {
            part[j] += __shfl_xor(part[j], 16);
            part[j] += __shfl_xor(part[j], 32);
        }
        if (g == 0) {
#pragma unroll
            for (int j = 0; j < 4; ++j)
                atomicAdd(&rns[it & 1][lr * 4 + j], part[j]);
        }
        // prefetch next tile (loads stay in flight across barriers)
        if (it + 1 < cnt) {
            const int t2 = tau + 1;
            const float* xb2 = x + (size_t)(t2 >> 8) * C_ * S_ + ((t2 & 255) << 6);
#pragma unroll
            for (int i = 0; i < 2; ++i)
#pragma unroll
                for (int cc = 0; cc < 4; ++cc)
                    pre[i][cc] = *(const float4*)(xb2 + (size_t)(cqv[i] * 4 + cc) * S_ + s4 * 4);
        }
        __syncthreads();   // B: xT/xC/rns visible

        // ---- logits GEMM: D[s][k], wave w owns s-rows [16w,16w+16) ----
        f32x4 acc[4];
#pragma unroll
        for (int nt = 0; nt < 4; ++nt) acc[nt] = (f32x4){0.f, 0.f, 0.f, 0.f};
        __builtin_amdgcn_s_setprio(1);
#pragma unroll
        for (int kt = 0; kt < 4; ++kt) {
            const int co = kt * 32 + g * 8;
            const int sa = w * 16 + lr;
            f16x8 af = *(const f16x8*)&xT[sa * 128 + (co ^ SWZ_S(sa))];
#pragma unroll
            for (int nt = 0; nt < 4; ++nt)
                acc[nt] = __builtin_amdgcn_mfma_f32_16x16x32_f16(af, wfrag[nt][kt], acc[nt], 0, 0, 0);
        }
        __builtin_amdgcn_s_setprio(0);

        // ---- softmax over k (4 nt regs x 16 lr lanes), soft' -> sst ----
        {
            float rnl[4], ai[4];
#pragma unroll
            for (int r = 0; r < 4; ++r) {
                float ss = rns[it & 1][w * 16 + g * 4 + r];
                rnl[r] = 1.0f / fmaxf(sqrtf(ss), 1e-12f);
            }
#pragma unroll
            for (int nt = 0; nt < 4; ++nt)
#pragma unroll
                for (int r = 0; r < 4; ++r)
                    acc[nt][r] = __expf(acc[nt][r] * rnl[r] + bias[nt]);
#pragma unroll
            for (int r = 0; r < 4; ++r) {
                float sum = (acc[0][r] + acc[1][r]) + (acc[2][r] + acc[3][r]);
                sum += __shfl_xor(sum, 1);
                sum += __shfl_xor(sum, 2);
                sum += __shfl_xor(sum, 4);
                sum += __shfl_xor(sum, 8);
                float bi = 1.0f / sum;
                ai[r] = bi * rnl[r];
#pragma unroll
                for (int nt = 0; nt < 4; ++nt) a_acc[nt] += acc[nt][r] * bi;
            }
#pragma unroll
            for (int nt = 0; nt < 4; ++nt) {
                int k = nt * 16 + lr;
                int sloc = w * 16 + g * 4;
                f16x4 p = {(_Float16)(acc[nt][0] * ai[0]), (_Float16)(acc[nt][1] * ai[1]),
                           (_Float16)(acc[nt][2] * ai[2]), (_Float16)(acc[nt][3] * ai[3])};
                *(f16x4*)&sst[k * 64 + (sloc ^ ((k & 7) << 3))] = p;
            }
        }
        // rotation-zero the OTHER rns buffer (last read at softmax(it-1))
        if (tid < 64) rns[(it + 1) & 1][tid] = 0.f;
        __syncthreads();   // C: sst visible

        // ---- vlad GEMM: D[k][c], wave w owns k-tile w; accumulate vacc ----
        __builtin_amdgcn_s_setprio(1);
#pragma unroll
        for (int kt = 0; kt < 2; ++kt) {
            const int so = kt * 32 + g * 8;
            f16x8 pa = *(const f16x8*)&sst[(w * 16 + lr) * 64 + (so ^ fsw)];
#pragma unroll
            for (int nt = 0; nt < 8; ++nt) {
                f16x8 xv = *(const f16x8*)&xC[(nt * 16 + lr) * 64 + (so ^ fsw)];
                vacc[nt] = __builtin_amdgcn_mfma_f32_16x16x32_f16(pa, xv, vacc[nt], 0, 0, 0);
            }
        }
        __builtin_amdgcn_s_setprio(0);
    }
    flush(ncur);
}

// ---------------------------------------------------------------------------
// Finalize: vlad -= a_sum*centroids; intra-norm over C; global norm.
// Grid 16 x 1024. Thread t: k = t>>4, q = t&15, c = q + 16j (j<8).
// ---------------------------------------------------------------------------
__global__ __launch_bounds__(1024) void finalize_kernel(
    const float* __restrict__ vlad_sum, const float* __restrict__ a_sum,
    const float* __restrict__ centroids, float* __restrict__ out)
{
    __shared__ float red[16];
    const int n = blockIdx.x;
    const int t = threadIdx.x;
    const int k = t >> 4, q = t & 15;
    const float av = a_sum[n * K_ + k];

    const float* vp = vlad_sum + (size_t)n * (K_ * C_) + k * C_;
    const float* cp = centroids + k * C_;
    float v[8];
    float ssq = 0.f;
#pragma unroll
    for (int j = 0; j < 8; ++j) {
        int c = q + 16 * j;
        float val = vp[c] - av * cp[c];
        v[j] = val;
        ssq += val * val;
    }
    ssq += __shfl_xor(ssq, 1);
    ssq += __shfl_xor(ssq, 2);
    ssq += __shfl_xor(ssq, 4);
    ssq += __shfl_xor(ssq, 8);
    const float inv1 = 1.0f / fmaxf(sqrtf(ssq), 1e-12f);

    float gp = (q == 0) ? ssq * inv1 * inv1 : 0.f;
#pragma unroll
    for (int off = 1; off < 64; off <<= 1) gp += __shfl_xor(gp, off);
    if ((t & 63) == 0) red[t >> 6] = gp;
    __syncthreads();
    float G = 0.f;
#pragma unroll
    for (int i = 0; i < 16; ++i) G += red[i];
    const float ginv = 1.0f / fmaxf(sqrtf(G), 1e-12f);

    float* op = out + (size_t)n * (K_ * C_) + k * C_;
#pragma unroll
    for (int j = 0; j < 8; ++j) op[q + 16 * j] = v[j] * inv1 * ginv;
}

extern "C" void kernel_launch(void* const* d_in, const int* in_sizes, int n_in,
                              void* d_out, int out_size, void* d_ws, size_t ws_size,
                              hipStream_t stream) {
    const float* x     = (const float*)d_in[0];
    const float* fc_w  = (const float*)d_in[1];
    const float* fc_b  = (const float*)d_in[2];
    const float* cent  = (const float*)d_in[3];
    float* out = (float*)d_out;

    char* ws = (char*)d_ws;
    float* a_sum = (float*)ws;                 // 4 KB (N*K = 1024 floats)
    float* vlad  = (float*)(ws + 4096);        // 512 KB

    hipMemsetAsync(ws, 0, 4096 + (size_t)N_ * K_ * C_ * sizeof(float), stream);

    fused_kernel<<<768, 256, 0, stream>>>(x, fc_w, fc_b, vlad, a_sum);
    finalize_kernel<<<N_, 1024, 0, stream>>>(vlad, a_sum, cent, out);
}

// Round 8
// 72.216 us; speedup vs baseline: 1.4566x; 1.4566x over previous
//
#include <hip/hip_runtime.h>
#include <hip/hip_fp16.h>

#define N_ 16
#define C_ 128
#define S_ 16384
#define K_ 64

typedef __attribute__((ext_vector_type(4))) float f32x4;
typedef __attribute__((ext_vector_type(8))) _Float16 f16x8;
typedef __attribute__((ext_vector_type(4))) _Float16 f16x4;

// xT row-swizzle: varies with staging rows s=4*s4+j AND frag rows s=16m+lr.
#define SWZ_S(s) ((((s) ^ ((s) >> 3)) & 7) << 3)

// ---------------------------------------------------------------------------
// Fused v5: v4 structure, but launch_bounds(256,2) — round 7's (256,3) forced
// the allocator to the 85-VGPR tier and spilled wfrag (FETCH 66->171MB).
// With (256,2) the allocator historically picks ~140 VGPR -> 3 waves/SIMD by
// HW granule, and LDS 40.5KB -> 3 blocks/CU. Grid 768 = exactly 3/CU.
// ---------------------------------------------------------------------------
__global__ __launch_bounds__(256, 2) void fused_kernel(
    const float* __restrict__ x, const float* __restrict__ fc_w,
    const float* __restrict__ fc_b, float* __restrict__ vlad_acc,
    float* __restrict__ a_sum)
{
    __shared__ _Float16 xT[64 * 128];    // 16 KB [s][c]
    __shared__ _Float16 xC[128 * 64];    // 16 KB [c][s]
    __shared__ _Float16 sst[64 * 64];    //  8 KB [k][s]
    __shared__ float rns[2][64];         // 512 B, rotation-zeroed

    const int tid = threadIdx.x;
    const int lane = tid & 63, w = tid >> 6;
    const int lr = lane & 15, g = lane >> 4;
    const int fsw = (lr & 7) << 3;       // swizzle for rows of form m*16+lr

    // block's tile range: 256 blocks x 6 tiles + 512 blocks x 5 tiles = 4096
    const int b = blockIdx.x;
    const int lo  = (b < 256) ? b * 6 : 1536 + (b - 256) * 5;
    const int cnt = (b < 256) ? 6 : 5;

    // ---- W B-fragments in registers (tile/n-invariant) ----
    f16x8 wfrag[4][4];
#pragma unroll
    for (int nt = 0; nt < 4; ++nt)
#pragma unroll
        for (int kt = 0; kt < 4; ++kt) {
            const float* wp = fc_w + (nt * 16 + lr) * C_ + kt * 32 + g * 8;
            float4 wa = *(const float4*)wp;
            float4 wb = *(const float4*)(wp + 4);
            f16x8 f;
            f[0] = (_Float16)wa.x; f[1] = (_Float16)wa.y;
            f[2] = (_Float16)wa.z; f[3] = (_Float16)wa.w;
            f[4] = (_Float16)wb.x; f[5] = (_Float16)wb.y;
            f[6] = (_Float16)wb.z; f[7] = (_Float16)wb.w;
            wfrag[nt][kt] = f;
        }
    if (tid < 128) (&rns[0][0])[tid] = 0.f;   // zero both rns buffers

    float bias[4];
#pragma unroll
    for (int nt = 0; nt < 4; ++nt) bias[nt] = fc_b[nt * 16 + lr];
    float a_acc[4] = {0.f, 0.f, 0.f, 0.f};
    f32x4 vacc[8];
#pragma unroll
    for (int nt = 0; nt < 8; ++nt) vacc[nt] = (f32x4){0.f, 0.f, 0.f, 0.f};

    const int s4 = tid & 15;
    int cqv[2];
#pragma unroll
    for (int i = 0; i < 2; ++i) cqv[i] = i * 16 + (tid >> 4);

    auto flush = [&](int nn) {
        float* vp = vlad_acc + ((size_t)nn * K_ + w * 16) * C_;
#pragma unroll
        for (int nt = 0; nt < 8; ++nt) {
#pragma unroll
            for (int r = 0; r < 4; ++r)
                atomicAdd(vp + (g * 4 + r) * C_ + nt * 16 + lr, vacc[nt][r]);
            vacc[nt] = (f32x4){0.f, 0.f, 0.f, 0.f};
        }
#pragma unroll
        for (int nt = 0; nt < 4; ++nt) {
            a_acc[nt] += __shfl_xor(a_acc[nt], 16);
            a_acc[nt] += __shfl_xor(a_acc[nt], 32);
        }
        if (lane < 16) {
#pragma unroll
            for (int nt = 0; nt < 4; ++nt)
                atomicAdd(a_sum + nn * K_ + nt * 16 + lr, a_acc[nt]);
        }
#pragma unroll
        for (int nt = 0; nt < 4; ++nt) a_acc[nt] = 0.f;
    };

    // prefetch first tile
    float4 pre[2][4];
    {
        const int n0 = lo >> 8, ss = (lo & 255) << 6;
        const float* xb = x + (size_t)n0 * C_ * S_ + ss;
#pragma unroll
        for (int i = 0; i < 2; ++i)
#pragma unroll
            for (int cc = 0; cc < 4; ++cc)
                pre[i][cc] = *(const float4*)(xb + (size_t)(cqv[i] * 4 + cc) * S_ + s4 * 4);
    }

    int ncur = lo >> 8;

#pragma unroll 1
    for (int it = 0; it < cnt; ++it) {
        const int tau = lo + it;
        const int n = tau >> 8;
        if (n != ncur) { flush(ncur); ncur = n; }   // reg-private, no sync needed

        __syncthreads();   // A: xT/xC/sst free (vlad(it-1) done); rns init @it=0

        // ---- stage tile: xT (4x4 transpose) + xC + norm partials ----
        float part[4] = {0.f, 0.f, 0.f, 0.f};
#pragma unroll
        for (int i = 0; i < 2; ++i) {
            int cq = cqv[i];
#pragma unroll
            for (int j = 0; j < 4; ++j) {
                float v0 = (&pre[i][0].x)[j], v1 = (&pre[i][1].x)[j],
                      v2 = (&pre[i][2].x)[j], v3 = (&pre[i][3].x)[j];
                part[j] += v0 * v0 + v1 * v1 + v2 * v2 + v3 * v3;
                f16x4 p = {(_Float16)v0, (_Float16)v1, (_Float16)v2, (_Float16)v3};
                int s = s4 * 4 + j;
                *(f16x4*)&xT[s * 128 + ((cq * 4) ^ SWZ_S(s))] = p;
            }
#pragma unroll
            for (int cc = 0; cc < 4; ++cc) {
                int c = cq * 4 + cc;
                f16x4 q = {(_Float16)pre[i][cc].x, (_Float16)pre[i][cc].y,
                           (_Float16)pre[i][cc].z, (_Float16)pre[i][cc].w};
                *(f16x4*)&xC[c * 64 + ((s4 * 4) ^ ((c & 7) << 3))] = q;
            }
        }
#pragma unroll
        for (int j = 0; j < 4; ++j) {
            part[j] += __shfl_xor(part[j], 16);
            part[j] += __shfl_xor(part[j], 32);
        }
        if (g == 0) {
#pragma unroll
            for (int j = 0; j < 4; ++j)
                atomicAdd(&rns[it & 1][lr * 4 + j], part[j]);
        }
        // prefetch next tile (loads stay in flight across barriers)
        if (it + 1 < cnt) {
            const int t2 = tau + 1;
            const float* xb2 = x + (size_t)(t2 >> 8) * C_ * S_ + ((t2 & 255) << 6);
#pragma unroll
            for (int i = 0; i < 2; ++i)
#pragma unroll
                for (int cc = 0; cc < 4; ++cc)
                    pre[i][cc] = *(const float4*)(xb2 + (size_t)(cqv[i] * 4 + cc) * S_ + s4 * 4);
        }
        __syncthreads();   // B: xT/xC/rns visible

        // ---- logits GEMM: D[s][k], wave w owns s-rows [16w,16w+16) ----
        f32x4 acc[4];
#pragma unroll
        for (int nt = 0; nt < 4; ++nt) acc[nt] = (f32x4){0.f, 0.f, 0.f, 0.f};
        __builtin_amdgcn_s_setprio(1);
#pragma unroll
        for (int kt = 0; kt < 4; ++kt) {
            const int co = kt * 32 + g * 8;
            const int sa = w * 16 + lr;
            f16x8 af = *(const f16x8*)&xT[sa * 128 + (co ^ SWZ_S(sa))];
#pragma unroll
            for (int nt = 0; nt < 4; ++nt)
                acc[nt] = __builtin_amdgcn_mfma_f32_16x16x32_f16(af, wfrag[nt][kt], acc[nt], 0, 0, 0);
        }
        __builtin_amdgcn_s_setprio(0);

        // ---- softmax over k (4 nt regs x 16 lr lanes), soft' -> sst ----
        {
            float rnl[4], ai[4];
#pragma unroll
            for (int r = 0; r < 4; ++r) {
                float ss = rns[it & 1][w * 16 + g * 4 + r];
                rnl[r] = 1.0f / fmaxf(sqrtf(ss), 1e-12f);
            }
#pragma unroll
            for (int nt = 0; nt < 4; ++nt)
#pragma unroll
                for (int r = 0; r < 4; ++r)
                    acc[nt][r] = __expf(acc[nt][r] * rnl[r] + bias[nt]);
#pragma unroll
            for (int r = 0; r < 4; ++r) {
                float sum = (acc[0][r] + acc[1][r]) + (acc[2][r] + acc[3][r]);
                sum += __shfl_xor(sum, 1);
                sum += __shfl_xor(sum, 2);
                sum += __shfl_xor(sum, 4);
                sum += __shfl_xor(sum, 8);
                float bi = 1.0f / sum;
                ai[r] = bi * rnl[r];
#pragma unroll
                for (int nt = 0; nt < 4; ++nt) a_acc[nt] += acc[nt][r] * bi;
            }
#pragma unroll
            for (int nt = 0; nt < 4; ++nt) {
                int k = nt * 16 + lr;
                int sloc = w * 16 + g * 4;
                f16x4 p = {(_Float16)(acc[nt][0] * ai[0]), (_Float16)(acc[nt][1] * ai[1]),
                           (_Float16)(acc[nt][2] * ai[2]), (_Float16)(acc[nt][3] * ai[3])};
                *(f16x4*)&sst[k * 64 + (sloc ^ ((k & 7) << 3))] = p;
            }
        }
        // rotation-zero the OTHER rns buffer (last read at softmax(it-1))
        if (tid < 64) rns[(it + 1) & 1][tid] = 0.f;
        __syncthreads();   // C: sst visible

        // ---- vlad GEMM: D[k][c], wave w owns k-tile w; accumulate vacc ----
        __builtin_amdgcn_s_setprio(1);
#pragma unroll
        for (int kt = 0; kt < 2; ++kt) {
            const int so = kt * 32 + g * 8;
            f16x8 pa = *(const f16x8*)&sst[(w * 16 + lr) * 64 + (so ^ fsw)];
#pragma unroll
            for (int nt = 0; nt < 8; ++nt) {
                f16x8 xv = *(const f16x8*)&xC[(nt * 16 + lr) * 64 + (so ^ fsw)];
                vacc[nt] = __builtin_amdgcn_mfma_f32_16x16x32_f16(pa, xv, vacc[nt], 0, 0, 0);
            }
        }
        __builtin_amdgcn_s_setprio(0);
    }
    flush(ncur);
}

// ---------------------------------------------------------------------------
// Finalize: vlad -= a_sum*centroids; intra-norm over C; global norm.
// Grid 16 x 1024. Thread t: k = t>>4, q = t&15, c = q + 16j (j<8).
// ---------------------------------------------------------------------------
__global__ __launch_bounds__(1024) void finalize_kernel(
    const float* __restrict__ vlad_sum, const float* __restrict__ a_sum,
    const float* __restrict__ centroids, float* __restrict__ out)
{
    __shared__ float red[16];
    const int n = blockIdx.x;
    const int t = threadIdx.x;
    const int k = t >> 4, q = t & 15;
    const float av = a_sum[n * K_ + k];

    const float* vp = vlad_sum + (size_t)n * (K_ * C_) + k * C_;
    const float* cp = centroids + k * C_;
    float v[8];
    float ssq = 0.f;
#pragma unroll
    for (int j = 0; j < 8; ++j) {
        int c = q + 16 * j;
        float val = vp[c] - av * cp[c];
        v[j] = val;
        ssq += val * val;
    }
    ssq += __shfl_xor(ssq, 1);
    ssq += __shfl_xor(ssq, 2);
    ssq += __shfl_xor(ssq, 4);
    ssq += __shfl_xor(ssq, 8);
    const float inv1 = 1.0f / fmaxf(sqrtf(ssq), 1e-12f);

    float gp = (q == 0) ? ssq * inv1 * inv1 : 0.f;
#pragma unroll
    for (int off = 1; off < 64; off <<= 1) gp += __shfl_xor(gp, off);
    if ((t & 63) == 0) red[t >> 6] = gp;
    __syncthreads();
    float G = 0.f;
#pragma unroll
    for (int i = 0; i < 16; ++i) G += red[i];
    const float ginv = 1.0f / fmaxf(sqrtf(G), 1e-12f);

    float* op = out + (size_t)n * (K_ * C_) + k * C_;
#pragma unroll
    for (int j = 0; j < 8; ++j) op[q + 16 * j] = v[j] * inv1 * ginv;
}

extern "C" void kernel_launch(void* const* d_in, const int* in_sizes, int n_in,
                              void* d_out, int out_size, void* d_ws, size_t ws_size,
                              hipStream_t stream) {
    const float* x     = (const float*)d_in[0];
    const float* fc_w  = (const float*)d_in[1];
    const float* fc_b  = (const float*)d_in[2];
    const float* cent  = (const float*)d_in[3];
    float* out = (float*)d_out;

    char* ws = (char*)d_ws;
    float* a_sum = (float*)ws;                 // 4 KB (N*K = 1024 floats)
    float* vlad  = (float*)(ws + 4096);        // 512 KB

    hipMemsetAsync(ws, 0, 4096 + (size_t)N_ * K_ * C_ * sizeof(float), stream);

    fused_kernel<<<768, 256, 0, stream>>>(x, fc_w, fc_b, vlad, a_sum);
    finalize_kernel<<<N_, 1024, 0, stream>>>(vlad, a_sum, cent, out);
}